// Round 16
// baseline (113.975 us; speedup 1.0000x reference)
//
#include <hip/hip_runtime.h>

typedef __attribute__((ext_vector_type(8))) short bf16x8;
typedef __attribute__((ext_vector_type(4))) float f32x4;
typedef __attribute__((ext_vector_type(16))) float f32x16;
typedef __attribute__((ext_vector_type(4))) short short4v;
typedef __attribute__((ext_vector_type(4))) unsigned int uint4v;

#define B_  2
#define T_  2048
#define D_  1024
#define H_  16
#define HD_ 64

__device__ inline short f2bf(float f){
  unsigned u = __builtin_bit_cast(unsigned, f);
  u += 0x7fff + ((u >> 16) & 1);          // round-to-nearest-even
  return (short)(u >> 16);
}
__device__ inline float bf2f(short s){
  unsigned u = ((unsigned)(unsigned short)s) << 16;
  return __builtin_bit_cast(float, u);
}

__device__ inline void gl2lds16(const void* g, void* l){
  __builtin_amdgcn_global_load_lds(
      (const __attribute__((address_space(1))) unsigned int*)g,
      (__attribute__((address_space(3))) unsigned int*)l, 16, 0, 0);
}

// ---------------- fused prep: x->bf16, W1->W1T bf16, W2->W2T bf16 ----------
__device__ inline void transpose_tile(const float* __restrict__ in,
                                      short* __restrict__ out,
                                      int R, int C, int bx, int by){
  __shared__ float tile[32][33];
  int tx = threadIdx.x & 31, ty0 = threadIdx.x >> 5;
#pragma unroll
  for (int i = 0; i < 4; i++){
    int ty = ty0 + i * 8;
    tile[ty][tx] = in[(by + ty) * C + bx + tx];
  }
  __syncthreads();
#pragma unroll
  for (int i = 0; i < 4; i++){
    int ty = ty0 + i * 8;
    out[(bx + ty) * R + by + tx] = f2bf(tile[tx][ty]);
  }
}

__global__ __launch_bounds__(256) void prep(
    const float* __restrict__ x,  short* __restrict__ xb,
    const float* __restrict__ W1, short* __restrict__ W1T,
    const float* __restrict__ W2, short* __restrict__ W2T){
  const int bid = blockIdx.x;
  if (bid < 4096){
    int i = (bid * 256 + threadIdx.x) * 4;
    float4 v = *(const float4*)(x + i);
    short4v o;
    o[0] = f2bf(v.x); o[1] = f2bf(v.y); o[2] = f2bf(v.z); o[3] = f2bf(v.w);
    *(short4v*)(xb + i) = o;
  } else if (bid < 4096 + 3072){
    int tb = bid - 4096;                       // W1 [1024][3072] -> W1T
    transpose_tile(W1, W1T, 1024, 3072, (tb % 96) << 5, (tb / 96) << 5);
  } else {
    int tb = bid - 7168;                       // W2 [1024][1024] -> W2T
    transpose_tile(W2, W2T, 1024, 1024, (tb % 32) << 5, (tb / 32) << 5);
  }
}

// Q pre-scale: 1/sqrt(64) * log2(e)  (softmax runs in exp2 domain)
#define QSCALE 0.18033688011112042f

// ---------------- QKV GEMM: m201 8-phase / 2-Ktile-per-iter template ------
// 256^2 tile, BK=64, 8 waves (2Mx4N), per-wave C=128x64 (acc 8x4).
// Fixed slots: slot0 = even K-tiles, slot1 = odd.  8 phases/iter, each:
// {ds_read quadrant | issue 1 half-tile stage (2 gl2lds) | barrier |
//  lgkmcnt(0) | 16 MFMA (setprio) | barrier}; vmcnt(4) ONLY at ph4/ph8.
// Stage placement (after each region's last ds_read, barrier-separated):
//  p1,p2: A->slot1 (this iter's p5 data); p3,p4: B->slot0 (next iter);
//  p5,p6: A->slot0 (next iter); p7,p8: B->slot1 (next iter).
// Out-of-range K-tiles stage into Dummy LDS (keeps vmcnt counts exact).
__global__ __launch_bounds__(512) void gemm_qkv8(
    const short* __restrict__ A, const short* __restrict__ Bt,
    const float* __restrict__ bias,
    short* __restrict__ q, short* __restrict__ kk, short* __restrict__ vT){
  constexpr int K_ = 1024, NT = 16, NITER = 8;
  __shared__ short As[2][256 * 64];   // 64 KB
  __shared__ short Bs[2][256 * 64];   // 64 KB
  __shared__ short Dm[128 * 64];      // 16 KB dummy stage target
  const int tid = threadIdx.x;
  const int lane = tid & 63, w = tid >> 6;
  const int wm = w >> 2, wn = w & 3;
  const int lr = lane & 15, lk = lane >> 4;
  const int brow = blockIdx.y * 256, bcol = blockIdx.x * 256;
  const short* Ag = A  + brow * K_;
  const short* Bg = Bt + bcol * K_;
  f32x4 acc[8][4] = {};
  bf16x8 aF[8], bFc0[4], bFc1[4];

  auto unitA = [&](int s, int h, int kt){
    const bool dm = kt >= NT;
    const int k0 = (dm ? NT - 1 : kt) * 64;
#pragma unroll
    for (int j = 0; j < 2; j++){
      int idx = j * 512 + tid;                 // [0,1024)
      int row = h * 128 + (idx >> 3);
      int colb = (idx & 7) * 16;
      int cs = colb ^ ((row & 7) << 4);
      char* dst = dm ? ((char*)Dm + idx * 16) : ((char*)As[s] + row * 128 + colb);
      gl2lds16(Ag + row * K_ + k0 + (cs >> 1), dst);
    }
  };
  auto unitB = [&](int s, int h, int kt){
    const bool dm = kt >= NT;
    const int k0 = (dm ? NT - 1 : kt) * 64;
#pragma unroll
    for (int j = 0; j < 2; j++){
      int idx = j * 512 + tid;
      int row = h * 128 + (idx >> 3);
      int colb = (idx & 7) * 16;
      int cs = colb ^ ((row & 7) << 4);
      char* dst = dm ? ((char*)Dm + idx * 16) : ((char*)Bs[s] + row * 128 + colb);
      gl2lds16(Bg + row * K_ + k0 + (cs >> 1), dst);
    }
  };
  auto loadA = [&](const short* Ac, int r){
#pragma unroll
    for (int mf = 0; mf < 4; mf++){
      int row = wm * 128 + r * 64 + mf * 16 + lr;
      const char* rp = (const char*)Ac + row * 128;
      int swz = (row & 7) << 4;
#pragma unroll
      for (int kx = 0; kx < 2; kx++)
        aF[mf * 2 + kx] = *(const bf16x8*)(rp + ((kx * 64 + lk * 16) ^ swz));
    }
  };
  auto loadB = [&](const short* Bc, int c, bf16x8* dst){
#pragma unroll
    for (int nf = 0; nf < 2; nf++){
      int row = wn * 64 + c * 32 + nf * 16 + lr;
      const char* rp = (const char*)Bc + row * 128;
      int swz = (row & 7) << 4;
#pragma unroll
      for (int kx = 0; kx < 2; kx++)
        dst[nf * 2 + kx] = *(const bf16x8*)(rp + ((kx * 64 + lk * 16) ^ swz));
    }
  };

#define MFMA16(r, c, B)                                                      \
  _Pragma("unroll")                                                          \
  for (int mf = 0; mf < 4; mf++)                                             \
    _Pragma("unroll")                                                        \
    for (int nf = 0; nf < 2; nf++)                                           \
      _Pragma("unroll")                                                      \
      for (int kx = 0; kx < 2; kx++)                                         \
        acc[(r)*4 + mf][(c)*2 + nf] = __builtin_amdgcn_mfma_f32_16x16x32_bf16(\
            aF[mf*2+kx], (B)[nf*2+kx], acc[(r)*4 + mf][(c)*2 + nf], 0, 0, 0);

#define PHASE_TAIL(R, C, BREG, GATE)                                         \
  __builtin_amdgcn_sched_barrier(0);                                         \
  __builtin_amdgcn_s_barrier();                                              \
  asm volatile("s_waitcnt lgkmcnt(0)" ::: "memory");                         \
  __builtin_amdgcn_sched_barrier(0);                                         \
  __builtin_amdgcn_s_setprio(1);                                             \
  MFMA16(R, C, BREG)                                                         \
  __builtin_amdgcn_s_setprio(0);                                             \
  __builtin_amdgcn_sched_barrier(0);                                         \
  if (GATE) asm volatile("s_waitcnt vmcnt(4)" ::: "memory");                 \
  __builtin_amdgcn_s_barrier();                                              \
  __builtin_amdgcn_sched_barrier(0);

  // prologue: slot0 <- K0 (B then A), slot1-B <- K1.  6 units, 12 loads.
  unitB(0, 0, 0); unitB(0, 1, 0);
  unitA(0, 0, 0); unitA(0, 1, 0);
  unitB(1, 0, 1); unitB(1, 1, 1);
  asm volatile("s_waitcnt vmcnt(4)" ::: "memory");   // slot0 K0 landed
  __builtin_amdgcn_s_barrier();
  __builtin_amdgcn_sched_barrier(0);

  for (int it = 0; it < NITER; ++it){
    const int kA1 = 2 * it + 1;     // slot1-A, consumed this iter p5-p8
    const int kS0 = 2 * it + 2;     // slot0 restage (next iter)
    const int kB1 = 2 * it + 3;     // slot1-B restage (next iter)
    // p1: ds A0-r0 + B0-c0 ; stage A1-h0
    loadA(As[0], 0); loadB(Bs[0], 0, bFc0);
    unitA(1, 0, kA1);
    PHASE_TAIL(0, 0, bFc0, false)
    // p2: ds B0-c1 ; stage A1-h1
    loadB(Bs[0], 1, bFc1);
    unitA(1, 1, kA1);
    PHASE_TAIL(0, 1, bFc1, false)
    // p3: ds A0-r1 ; stage B0-h0
    loadA(As[0], 1);
    unitB(0, 0, kS0);
    PHASE_TAIL(1, 0, bFc0, false)
    // p4: stage B0-h1 ; GATE vmcnt(4) -> slot1 ready for p5
    unitB(0, 1, kS0);
    PHASE_TAIL(1, 1, bFc1, true)
    // p5: ds A1-r0 + B1-c0 ; stage A0-h0
    loadA(As[1], 0); loadB(Bs[1], 0, bFc0);
    unitA(0, 0, kS0);
    PHASE_TAIL(0, 0, bFc0, false)
    // p6: ds B1-c1 ; stage A0-h1
    loadB(Bs[1], 1, bFc1);
    unitA(0, 1, kS0);
    PHASE_TAIL(0, 1, bFc1, false)
    // p7: ds A1-r1 ; stage B1-h0
    loadA(As[1], 1);
    unitB(1, 0, kB1);
    PHASE_TAIL(1, 0, bFc0, false)
    // p8: stage B1-h1 ; GATE vmcnt(4) -> slot0 ready for next p1
    unitB(1, 1, kB1);
    PHASE_TAIL(1, 1, bFc1, true)
  }
  asm volatile("s_waitcnt vmcnt(0)" ::: "memory");   // drain dummies

  // epilogue: scatter to q (scaled), k, vT.  acc[a][cn]:
  // row = brow + wm*128 + (a>>2)*64 + (a&3)*16 + lk*4
  // col = bcol + wn*64 + (cn>>1)*32 + (cn&1)*16 + lr
#pragma unroll
  for (int cn = 0; cn < 4; cn++){
    int n = bcol + wn * 64 + (cn >> 1) * 32 + (cn & 1) * 16 + lr;
    float bv = bias[n];
    int sec = n >> 10, d = n & 1023, hh = d >> 6, hd = d & 63;
#pragma unroll
    for (int a = 0; a < 8; a++){
      int m0 = brow + wm * 128 + (a >> 2) * 64 + (a & 3) * 16 + lk * 4;
      int bb = m0 >> 11, t0 = m0 & 2047;
      int bh = bb * H_ + hh;
      if (sec == 0){
#pragma unroll
        for (int r = 0; r < 4; r++)
          q[(bh * T_ + t0 + r) * HD_ + hd] = f2bf((acc[a][cn][r] + bv) * QSCALE);
      } else if (sec == 1){
#pragma unroll
        for (int r = 0; r < 4; r++)
          kk[(bh * T_ + t0 + r) * HD_ + hd] = f2bf(acc[a][cn][r] + bv);
      } else {
        float v0 = acc[a][cn][0] + bv, v1 = acc[a][cn][1] + bv;
        float v2 = acc[a][cn][2] + bv, v3 = acc[a][cn][3] + bv;
        unsigned lo = (unsigned)(unsigned short)f2bf(v0) | ((unsigned)(unsigned short)f2bf(v1) << 16);
        unsigned hi = (unsigned)(unsigned short)f2bf(v2) | ((unsigned)(unsigned short)f2bf(v3) << 16);
        uint2 pk; pk.x = lo; pk.y = hi;
        *(uint2*)(vT + (bh * HD_ + hd) * T_ + t0) = pk;   // v stored transposed
      }
    }
  }
}

// ---------------- proj GEMM: 3-buffer 128^2 (round-9 structure) -----------
#define BM 128
#define BN 128
#define BK 32

template<int N_, int K_>
__global__ __launch_bounds__(256, 3) void gemm_bt(
    const short* __restrict__ A, const short* __restrict__ Bt,
    const float* __restrict__ bias, float* __restrict__ outf){
  __shared__ short As[3][BM * BK];
  __shared__ short Bs[3][BN * BK];
  const int tid = threadIdx.x;
  const int lane = tid & 63, w = tid >> 6;
  const int wm = w >> 1, wn = w & 1;
  const int lr = lane & 15, lk = lane >> 4;
  const int brow = blockIdx.y * BM, bcol = blockIdx.x * BN;
  f32x4 acc[4][4] = {};
  const short* Ag = A  + brow * K_;
  const short* Bg = Bt + bcol * K_;

  auto stage = [&](int buf, int k0){
#pragma unroll
    for (int i = 0; i < 2; i++){
      int idx = i * 256 + tid;
      int row = idx >> 2, c8 = (idx & 3) * 8;   // 64B rows of 32 bf16
      gl2lds16(Ag + row * K_ + k0 + c8, (char*)As[buf] + idx * 16);
      gl2lds16(Bg + row * K_ + k0 + c8, (char*)Bs[buf] + idx * 16);
    }
  };

  const int NT = K_ / BK;
  stage(0, 0);
  stage(1, BK);
  for (int t = 0; t < NT; ++t){
    if (t + 1 < NT)
      asm volatile("s_waitcnt vmcnt(4)" ::: "memory");  // tile t landed (mine)
    else
      asm volatile("s_waitcnt vmcnt(0)" ::: "memory");
    __builtin_amdgcn_s_barrier();      // all waves: tile t landed, iter t-1 reads done
    __builtin_amdgcn_sched_barrier(0);
    if (t + 2 < NT)
      stage((t + 2) % 3, (t + 2) * BK);        // safe: buf last read at t-1
    __builtin_amdgcn_sched_barrier(0);

    const short* Ac = As[t % 3];
    const short* Bc = Bs[t % 3];
    bf16x8 a[4], b[4];
#pragma unroll
    for (int mf = 0; mf < 4; mf++)
      a[mf] = *(const bf16x8*)(Ac + (wm * 64 + mf * 16 + lr) * BK + lk * 8);
#pragma unroll
    for (int nf = 0; nf < 4; nf++)
      b[nf] = *(const bf16x8*)(Bc + (wn * 64 + nf * 16 + lr) * BK + lk * 8);
    __builtin_amdgcn_s_setprio(1);
#pragma unroll
    for (int mf = 0; mf < 4; mf++)
#pragma unroll
      for (int nf = 0; nf < 4; nf++)
        acc[mf][nf] = __builtin_amdgcn_mfma_f32_16x16x32_bf16(a[mf], b[nf], acc[mf][nf], 0, 0, 0);
    __builtin_amdgcn_s_setprio(0);
    // no end barrier: next iter's top barrier separates reads from restage
  }

#pragma unroll
  for (int nf = 0; nf < 4; nf++){
    int n = bcol + wn * 64 + nf * 16 + lr;
    float bv = bias[n];
#pragma unroll
    for (int mf = 0; mf < 4; mf++){
      int m0 = brow + wm * 64 + mf * 16 + lk * 4;
#pragma unroll
      for (int r = 0; r < 4; r++)
        outf[(m0 + r) * N_ + n] = acc[mf][nf][r] + bv;
    }
  }
}

// ---------------- causal flash attention, 32x32 swapped-QK^T ----------------
// NS=4 kv-chunked split; partials Op bf16 + ml f32; merged by attn_merge.
__device__ inline int crow(int r, int h){ return (r & 3) + 8 * (r >> 2) + 4 * h; }

template<int NS>
__global__ __launch_bounds__(256, 4) void attn32(
    const short* __restrict__ Q, const short* __restrict__ Kg,
    const short* __restrict__ Vt, short* __restrict__ Y,
    short* __restrict__ Op, float* __restrict__ ml){
  __shared__ short Ks[2][64 * 64];
  __shared__ short Vs[2][64 * 64];
  __shared__ float bounce[4][32];
  const int tid = threadIdx.x;
  const int w = tid >> 6, l = tid & 63;
  const int lq = l & 31, h = l >> 5;
  const int bx = blockIdx.x;
  int i, hf;
  if constexpr (NS == 4){
    int u = bx >> 5, v = u & 15;
    i = (v < 8) ? 15 - v : v - 8;
    hf = u >> 4;
  } else {
    i = (bx < 256) ? 15 - (bx >> 5) : (bx >> 5) - 8;
    hf = 0;
  }
  const int bh = bx & 31;
  const int q0 = i * 128, qw = q0 + w * 32;
  const int nt = 2 * (i + 1);
  const int t0 = hf * nt / NS;
  const int t1 = (hf + 1) * nt / NS;

  // Q fragments (B-operand): qb[dk] = Q[qw+lq][16*dk + 8*h .. +7]
  bf16x8 qb[4];
  {
    const short* qbase = Q + (bh * T_ + qw + lq) * HD_;
#pragma unroll
    for (int dk = 0; dk < 4; dk++)
      qb[dk] = *(const bf16x8*)(qbase + dk * 16 + h * 8);
  }

  f32x16 o0 = {}, o1 = {};
  float m = -1e30f, ll = 0.f;

  auto stage = [&](int buf, int t){
#pragma unroll
    for (int j = 0; j < 2; j++){
      int idx = j * 256 + tid;
      int row = idx >> 3, cb = (idx & 7) * 16;     // 128B rows
      int cbs = cb ^ ((row & 7) << 4);
      gl2lds16(Kg + (bh * T_ + t * 64 + row) * HD_ + (cbs >> 1), (char*)Ks[buf] + idx * 16);
      gl2lds16(Vt + (bh * HD_ + row) * T_ + t * 64 + (cbs >> 1), (char*)Vs[buf] + idx * 16);
    }
  };

  if (t0 < t1){
    stage(0, t0);
    for (int t = t0; t < t1; ++t){
      const int cur = (t - t0) & 1;
      if (t + 1 < t1){
        stage(cur ^ 1, t + 1);                            // prefetch next tile
        asm volatile("s_waitcnt vmcnt(4)" ::: "memory");  // current tile landed
      } else {
        asm volatile("s_waitcnt vmcnt(0)" ::: "memory");
      }
      __builtin_amdgcn_s_barrier();
      __builtin_amdgcn_sched_barrier(0);

      const int kvb = t * 64;
      if (kvb <= qw + 31){                  // warp still below/on its diagonal
        const short* Kc = Ks[cur];
        const short* Vc = Vs[cur];

        // S^T = K . Q^T : s[kb] covers kv [kvb+32*kb, +32), q col = lq
        f32x16 s[2] = {};
        __builtin_amdgcn_s_setprio(1);
#pragma unroll
        for (int kb = 0; kb < 2; kb++){
          int row = kb * 32 + lq;
          const char* rp = (const char*)Kc + row * 128;
          int swz = (row & 7) << 4;
#pragma unroll
          for (int dk = 0; dk < 4; dk++){
            bf16x8 ka = *(const bf16x8*)(rp + ((dk * 32 + h * 16) ^ swz));
            s[kb] = __builtin_amdgcn_mfma_f32_32x32x16_bf16(ka, qb[dk], s[kb], 0, 0, 0);
          }
        }
        __builtin_amdgcn_s_setprio(0);

        const int qg = qw + lq;
        if (kvb + 63 > qw){                 // diagonal tile: causal mask
#pragma unroll
          for (int kb = 0; kb < 2; kb++)
#pragma unroll
            for (int r = 0; r < 16; r++){
              int kv = kvb + kb * 32 + crow(r, h);
              if (kv > qg) s[kb][r] = -1e30f;
            }
        }

        // row max: lane-local + 1 cross-half shuffle
        float pm = s[0][0];
#pragma unroll
        for (int r = 1; r < 16; r++) pm = fmaxf(pm, s[0][r]);
#pragma unroll
        for (int r = 0; r < 16; r++) pm = fmaxf(pm, s[1][r]);
        pm = fmaxf(pm, __shfl_xor(pm, 32));

        // defer-max (T13): rescale O only when max grew > 8 (log2 domain)
        if (__any(pm > m + 8.f)){
          float mn = fmaxf(pm, m);
          float sf = __builtin_amdgcn_exp2f(m - mn);
          m = mn;
          ll *= sf;
          bounce[w][lq] = sf;               // lanes l and l+32 write same value
#pragma unroll
          for (int r = 0; r < 16; r++){
            float sr = bounce[w][crow(r, h)];
            o0[r] *= sr; o1[r] *= sr;
          }
        }

        // P = 2^(s - m); row sum
        float ts = 0.f;
#pragma unroll
        for (int kb = 0; kb < 2; kb++)
#pragma unroll
          for (int r = 0; r < 16; r++){
            float p = __builtin_amdgcn_exp2f(s[kb][r] - m);
            s[kb][r] = p;
            ts += p;
          }
        ts += __shfl_xor(ts, 32);
        ll += ts;

        // pack P to bf16 pairs; pw0[kb*4+g] = kv kb*32+8g+4h'+{0,1}, pw1: +{2,3}
        unsigned pw0[8], pw1[8];
#pragma unroll
        for (int kb = 0; kb < 2; kb++)
#pragma unroll
          for (int gg = 0; gg < 4; gg++){
            unsigned r0, r1;
            asm("v_cvt_pk_bf16_f32 %0, %1, %2" : "=v"(r0) : "v"(s[kb][gg * 4 + 0]), "v"(s[kb][gg * 4 + 1]));
            asm("v_cvt_pk_bf16_f32 %0, %1, %2" : "=v"(r1) : "v"(s[kb][gg * 4 + 2]), "v"(s[kb][gg * 4 + 3]));
            pw0[kb * 4 + gg] = r0;
            pw1[kb * 4 + gg] = r1;
          }
        // swap(D=even, S=odd): D_hi <-> S_lo. even reg -> A-word0, odd -> A-word2.
#pragma unroll
        for (int ks = 0; ks < 4; ks++){
          asm("v_permlane32_swap_b32 %0, %1" : "+v"(pw0[2 * ks]), "+v"(pw0[2 * ks + 1]));
          asm("v_permlane32_swap_b32 %0, %1" : "+v"(pw1[2 * ks]), "+v"(pw1[2 * ks + 1]));
        }

        // O += P @ V
        __builtin_amdgcn_s_setprio(1);
#pragma unroll
        for (int ks = 0; ks < 4; ks++){
          uint4v paw;
          paw[0] = pw0[2 * ks];     paw[1] = pw1[2 * ks];
          paw[2] = pw0[2 * ks + 1]; paw[3] = pw1[2 * ks + 1];
          bf16x8 pa = __builtin_bit_cast(bf16x8, paw);
#pragma unroll
          for (int nb = 0; nb < 2; nb++){
            int row = nb * 32 + lq;
            bf16x8 vb = *(const bf16x8*)((const char*)Vc + row * 128 +
                          ((ks * 32 + h * 16) ^ ((row & 7) << 4)));
            if (nb == 0) o0 = __builtin_amdgcn_mfma_f32_32x32x16_bf16(pa, vb, o0, 0, 0, 0);
            else         o1 = __builtin_amdgcn_mfma_f32_32x32x16_bf16(pa, vb, o1, 0, 0, 0);
          }
        }
        __builtin_amdgcn_s_setprio(0);
      }
      __builtin_amdgcn_sched_barrier(0);
      __builtin_amdgcn_s_barrier();        // all reads of buf[cur] done
    }
  }

  if constexpr (NS == 4){
    // store unnormalized partials (bf16) + per-row (m, l)
    short* Oq = Op + ((size_t)(hf * 32 + bh)) * (size_t)T_ * 64;
    if (h == 0){
      float* mlr = ml + ((size_t)(hf * 32 + bh) * T_ + (qw + lq)) * 2;
      mlr[0] = m; mlr[1] = ll;
    }
#pragma unroll
    for (int r = 0; r < 16; r++){
      int qg = qw + crow(r, h);
      Oq[qg * 64 + lq]      = f2bf(o0[r]);
      Oq[qg * 64 + 32 + lq] = f2bf(o1[r]);
    }
  } else {
    // normalize by 1/l (broadcast via warp-private LDS) and store
    bounce[w][lq] = __builtin_amdgcn_rcpf(ll);
    const int b = bh >> 4, hh = bh & 15;
#pragma unroll
    for (int r = 0; r < 16; r++){
      int row = crow(r, h);
      float rl = bounce[w][row];
      int qg = qw + row;
      short* yb = Y + (b * T_ + qg) * D_ + hh * 64;
      yb[lq]      = f2bf(o0[r] * rl);
      yb[32 + lq] = f2bf(o1[r] * rl);
    }
  }
}

// ---------------- merge the four kv-split chunks ----------------
__global__ __launch_bounds__(256) void attn_merge(
    const short* __restrict__ Op, const float* __restrict__ ml,
    short* __restrict__ Y){
  int gid = blockIdx.x * 256 + threadIdx.x;
  int rid = gid >> 2, c16 = (gid & 3) * 16;
  float mh[4], lh[4];
#pragma unroll
  for (int hf = 0; hf < 4; hf++){
    float2 v = *(const float2*)(ml + (size_t)hf * 131072 + rid * 2);
    mh[hf] = v.x; lh[hf] = v.y;
  }
  float M = fmaxf(fmaxf(mh[0], mh[1]), fmaxf(mh[2], mh[3]));
  float f[4], den = 0.f;
#pragma unroll
  for (int hf = 0; hf < 4; hf++){
    f[hf] = __builtin_amdgcn_exp2f(mh[hf] - M);
    den += f[hf] * lh[hf];
  }
  float rl = 1.f / den;
  float acc[16] = {};
#pragma unroll
  for (int hf = 0; hf < 4; hf++){
    const short* o = Op + (size_t)hf * 4194304 + (size_t)rid * 64 + c16;
    bf16x8 a = *(const bf16x8*)(o);
    bf16x8 b = *(const bf16x8*)(o + 8);
    float fh = f[hf];
#pragma unroll
    for (int j = 0; j < 8; j++){
      acc[j]     += fh * bf2f(a[j]);
      acc[8 + j] += fh * bf2f(b[j]);
    }
  }
  int bh = rid >> 11, t = rid & 2047;
  short* yb = Y + (((bh >> 4) * T_ + t) * D_) + (bh & 15) * 64 + c16;
  bf16x8 o0, o1;
#pragma unroll
  for (int j = 0; j < 8; j++){
    o0[j] = f2bf(acc[j] * rl);
    o1[j] = f2bf(acc[8 + j] * rl);
  }
  *(bf16x8*)(yb)     = o0;
  *(bf16x8*)(yb + 8) = o1;
}

// ---------------- launch ----------------
extern "C" void kernel_launch(void* const* d_in, const int* in_sizes, int n_in,
                              void* d_out, int out_size, void* d_ws, size_t ws_size,
                              hipStream_t stream) {
  const float* x  = (const float*)d_in[0];
  const float* W1 = (const float*)d_in[1];
  const float* b1 = (const float*)d_in[2];
  const float* W2 = (const float*)d_in[3];
  const float* b2 = (const float*)d_in[4];
  float* out = (float*)d_out;

  char* ws = (char*)d_ws;
  short* W1T = (short*)(ws);                         // [3072][1024] bf16, 6 MB
  short* W2T = (short*)(ws + 6291456);               // [1024][1024] bf16, 2 MB
  short* xb  = (short*)(ws + 8388608);               // [4096][1024] bf16, 8 MB
  short* q   = (short*)(ws + 16777216);              // [B,H,T,64]  bf16, 8 MB
  short* kk  = (short*)(ws + 25165824);              // [B,H,T,64]  bf16, 8 MB
  short* vT  = (short*)(ws + 33554432);              // [B,H,64,T]  bf16, 8 MB
  short* Op  = (short*)(ws + 41943040);              // [4][32][2048][64] bf16, 32 MB
  float* mlb = (float*)(ws);                         // [4][32][2048][2] f32, 2 MB
                                                     //   overlays W1T (dead after QKV)
  short* y   = xb;                                   // alias: xb dead after QKV GEMM

  const size_t need = 41943040ull + 33554432ull;     // 72 MB
  const bool split = ws_size >= need;

  prep<<<dim3(8192), dim3(256), 0, stream>>>(x, xb, W1, W1T, W2, W2T);
  gemm_qkv8<<<dim3(12, 16), dim3(512), 0, stream>>>(xb, W1T, b1, q, kk, vT);
  if (split){
    attn32<4><<<dim3(2048), dim3(256), 0, stream>>>(q, kk, vT, nullptr, Op, mlb);
    attn_merge<<<dim3(1024), dim3(256), 0, stream>>>(Op, mlb, y);
  } else {
    attn32<1><<<dim3(512), dim3(256), 0, stream>>>(q, kk, vT, y, nullptr, nullptr);
  }
  gemm_bt<1024, 1024><<<dim3(8, 32), dim3(256), 0, stream>>>(y, W2T, b2, out);
}

// Round 17
// 110.470 us; speedup vs baseline: 1.0317x; 1.0317x over previous
//
#include <hip/hip_runtime.h>

typedef __attribute__((ext_vector_type(8))) short bf16x8;
typedef __attribute__((ext_vector_type(4))) float f32x4;
typedef __attribute__((ext_vector_type(16))) float f32x16;
typedef __attribute__((ext_vector_type(4))) short short4v;
typedef __attribute__((ext_vector_type(4))) unsigned int uint4v;

#define B_  2
#define T_  2048
#define D_  1024
#define H_  16
#define HD_ 64

__device__ inline short f2bf(float f){
  unsigned u = __builtin_bit_cast(unsigned, f);
  u += 0x7fff + ((u >> 16) & 1);          // round-to-nearest-even
  return (short)(u >> 16);
}
__device__ inline float bf2f(short s){
  unsigned u = ((unsigned)(unsigned short)s) << 16;
  return __builtin_bit_cast(float, u);
}

__device__ inline void gl2lds16(const void* g, void* l){
  __builtin_amdgcn_global_load_lds(
      (const __attribute__((address_space(1))) unsigned int*)g,
      (__attribute__((address_space(3))) unsigned int*)l, 16, 0, 0);
}

// ---------------- fused prep: x->bf16, W1->W1T bf16, W2->W2T bf16 ----------
__device__ inline void transpose_tile(const float* __restrict__ in,
                                      short* __restrict__ out,
                                      int R, int C, int bx, int by){
  __shared__ float tile[32][33];
  int tx = threadIdx.x & 31, ty0 = threadIdx.x >> 5;
#pragma unroll
  for (int i = 0; i < 4; i++){
    int ty = ty0 + i * 8;
    tile[ty][tx] = in[(by + ty) * C + bx + tx];
  }
  __syncthreads();
#pragma unroll
  for (int i = 0; i < 4; i++){
    int ty = ty0 + i * 8;
    out[(bx + ty) * R + by + tx] = f2bf(tile[tx][ty]);
  }
}

__global__ __launch_bounds__(256) void prep(
    const float* __restrict__ x,  short* __restrict__ xb,
    const float* __restrict__ W1, short* __restrict__ W1T,
    const float* __restrict__ W2, short* __restrict__ W2T){
  const int bid = blockIdx.x;
  if (bid < 4096){
    int i = (bid * 256 + threadIdx.x) * 4;
    float4 v = *(const float4*)(x + i);
    short4v o;
    o[0] = f2bf(v.x); o[1] = f2bf(v.y); o[2] = f2bf(v.z); o[3] = f2bf(v.w);
    *(short4v*)(xb + i) = o;
  } else if (bid < 4096 + 3072){
    int tb = bid - 4096;                       // W1 [1024][3072] -> W1T
    transpose_tile(W1, W1T, 1024, 3072, (tb % 96) << 5, (tb / 96) << 5);
  } else {
    int tb = bid - 7168;                       // W2 [1024][1024] -> W2T
    transpose_tile(W2, W2T, 1024, 1024, (tb % 32) << 5, (tb / 32) << 5);
  }
}

// Q pre-scale: 1/sqrt(64) * log2(e)  (softmax runs in exp2 domain)
#define QSCALE 0.18033688011112042f

// ---------------- QKV GEMM: 256x192, counted-vmcnt deep pipeline ----------
// A: 3 buffers (staged 2 tiles ahead), B: 2 buffers (1 tile ahead).
// Per-wave issue order A(t+1) < B(t+1) < A(t+2); tile-top wait vmcnt(4)
// (= A(t+1)'s newest loads stay in flight across the barrier -- T4, never 0
// until the last tile).  4 phases/tile: {ds_read quad | issue stage unit |
// barrier | 12 MFMA | barrier}.  T2 XOR-swizzle (verified: 0 conflicts).
// Session note: best of SIX schedule variants (40.4 us); plateau is
// shape-bound (K=1024, m102 curve), not schedule-bound.
__global__ __launch_bounds__(512) void gemm_qkv8(
    const short* __restrict__ A, const short* __restrict__ Bt,
    const float* __restrict__ bias,
    short* __restrict__ q, short* __restrict__ kk, short* __restrict__ vT){
  constexpr int K_ = 1024, NT = K_ / 64;
  __shared__ short As[3][256 * 64];   // 96 KB
  __shared__ short Bs[2][192 * 64];   // 48 KB
  const int tid = threadIdx.x;
  const int lane = tid & 63, w = tid >> 6;
  const int wm = w >> 2, wn = w & 3;
  const int lr = lane & 15, lk = lane >> 4;
  const int brow = blockIdx.y * 256, bcol = blockIdx.x * 192;
  const short* Ag = A  + brow * K_;
  const short* Bg = Bt + bcol * K_;
  f32x4 acc[8][3] = {};

  auto stageA = [&](int buf, int k0, int j){
    int idx = j * 512 + tid;
    int row = idx >> 3, cb = (idx & 7) * 16;
    int cs = cb ^ ((row & 7) << 4);
    gl2lds16(Ag + row * K_ + k0 + (cs >> 1), (char*)As[buf] + idx * 16);
  };
  auto stageB = [&](int buf, int k0, int j){
    int idx = j * 512 + tid;
    int row = idx >> 3, cb = (idx & 7) * 16;
    int cs = cb ^ ((row & 7) << 4);
    gl2lds16(Bg + row * K_ + k0 + (cs >> 1), (char*)Bs[buf] + idx * 16);
  };

  // prologue: A(0)->Abuf0, B(0)->Bbuf0, A(1)->Abuf1  (issue order matters)
#pragma unroll
  for (int j = 0; j < 4; j++) stageA(0, 0, j);
#pragma unroll
  for (int j = 0; j < 3; j++) stageB(0, 0, j);
#pragma unroll
  for (int j = 0; j < 4; j++) stageA(1, 64, j);

  for (int t = 0; t < NT; ++t){
    const short* Ac = As[t % 3];
    const short* Bc = Bs[t & 1];
    // tile-top wait: oldest (outstanding-4) loads = A(t)+B(t) complete;
    // A(t+1)'s 4 loads (newest) stay in flight across the barrier.
    if (t + 1 < NT)
      asm volatile("s_waitcnt vmcnt(4)" ::: "memory");
    else
      asm volatile("s_waitcnt vmcnt(0)" ::: "memory");
    __builtin_amdgcn_s_barrier();           // all waves' stages for tile t visible
    __builtin_amdgcn_sched_barrier(0);

    bf16x8 b[3][2];
#pragma unroll
    for (int p = 0; p < 4; p++){
      if (p == 0){
#pragma unroll
        for (int nf = 0; nf < 3; nf++){
          int rrow = wn * 48 + nf * 16 + lr;
          const char* rp = (const char*)Bc + rrow * 128;
          int swz = (rrow & 7) << 4;
#pragma unroll
          for (int kx = 0; kx < 2; kx++)
            b[nf][kx] = *(const bf16x8*)(rp + ((kx * 64 + lk * 16) ^ swz));
        }
      }
      bf16x8 a[2][2];
#pragma unroll
      for (int mf = 0; mf < 2; mf++){
        int arow = wm * 128 + p * 32 + mf * 16 + lr;
        const char* rp = (const char*)Ac + arow * 128;
        int swz = (arow & 7) << 4;
#pragma unroll
        for (int kx = 0; kx < 2; kx++)
          a[mf][kx] = *(const bf16x8*)(rp + ((kx * 64 + lk * 16) ^ swz));
      }
      // stage-issue: ph0-1 -> B(t+1) (3 loads), ph2-3 -> A(t+2) (4 loads)
      if (p == 0 && t + 1 < NT){ stageB((t + 1) & 1, (t + 1) * 64, 0); stageB((t + 1) & 1, (t + 1) * 64, 1); }
      else if (p == 1 && t + 1 < NT){ stageB((t + 1) & 1, (t + 1) * 64, 2); }
      else if (p == 2 && t + 2 < NT){ stageA((t + 2) % 3, (t + 2) * 64, 0); stageA((t + 2) % 3, (t + 2) * 64, 1); }
      else if (p == 3 && t + 2 < NT){ stageA((t + 2) % 3, (t + 2) * 64, 2); stageA((t + 2) % 3, (t + 2) * 64, 3); }
      __builtin_amdgcn_sched_barrier(0);
      __builtin_amdgcn_s_barrier();
      __builtin_amdgcn_sched_barrier(0);
      __builtin_amdgcn_s_setprio(1);
#pragma unroll
      for (int mf = 0; mf < 2; mf++)
#pragma unroll
        for (int nf = 0; nf < 3; nf++)
#pragma unroll
          for (int kx = 0; kx < 2; kx++)
            acc[p * 2 + mf][nf] = __builtin_amdgcn_mfma_f32_16x16x32_bf16(
                a[mf][kx], b[nf][kx], acc[p * 2 + mf][nf], 0, 0, 0);
      __builtin_amdgcn_s_setprio(0);
      __builtin_amdgcn_sched_barrier(0);
      __builtin_amdgcn_s_barrier();
      __builtin_amdgcn_sched_barrier(0);
    }
  }

  // epilogue: scatter to q (scaled), k, vT (per-lane sec; straddle-safe)
#pragma unroll
  for (int nf = 0; nf < 3; nf++){
    int n = bcol + wn * 48 + nf * 16 + lr;
    float bv = bias[n];
    int sec = n >> 10, d = n & 1023, h = d >> 6, hd = d & 63;
#pragma unroll
    for (int qd = 0; qd < 8; qd++){
      int m0 = brow + wm * 128 + qd * 16 + lk * 4;
      int bb = m0 >> 11, t0 = m0 & 2047;
      int bh = bb * H_ + h;
      if (sec == 0){
#pragma unroll
        for (int r = 0; r < 4; r++)
          q[(bh * T_ + t0 + r) * HD_ + hd] = f2bf((acc[qd][nf][r] + bv) * QSCALE);
      } else if (sec == 1){
#pragma unroll
        for (int r = 0; r < 4; r++)
          kk[(bh * T_ + t0 + r) * HD_ + hd] = f2bf(acc[qd][nf][r] + bv);
      } else {
        float v0 = acc[qd][nf][0] + bv, v1 = acc[qd][nf][1] + bv;
        float v2 = acc[qd][nf][2] + bv, v3 = acc[qd][nf][3] + bv;
        unsigned lo = (unsigned)(unsigned short)f2bf(v0) | ((unsigned)(unsigned short)f2bf(v1) << 16);
        unsigned hi = (unsigned)(unsigned short)f2bf(v2) | ((unsigned)(unsigned short)f2bf(v3) << 16);
        uint2 pk; pk.x = lo; pk.y = hi;
        *(uint2*)(vT + (bh * HD_ + hd) * T_ + t0) = pk;   // v stored transposed
      }
    }
  }
}

// ---------------- proj GEMM: 3-buffer 128^2 (round-9 structure) -----------
#define BM 128
#define BN 128
#define BK 32

template<int N_, int K_>
__global__ __launch_bounds__(256, 3) void gemm_bt(
    const short* __restrict__ A, const short* __restrict__ Bt,
    const float* __restrict__ bias, float* __restrict__ outf){
  __shared__ short As[3][BM * BK];
  __shared__ short Bs[3][BN * BK];
  const int tid = threadIdx.x;
  const int lane = tid & 63, w = tid >> 6;
  const int wm = w >> 1, wn = w & 1;
  const int lr = lane & 15, lk = lane >> 4;
  const int brow = blockIdx.y * BM, bcol = blockIdx.x * BN;
  f32x4 acc[4][4] = {};
  const short* Ag = A  + brow * K_;
  const short* Bg = Bt + bcol * K_;

  auto stage = [&](int buf, int k0){
#pragma unroll
    for (int i = 0; i < 2; i++){
      int idx = i * 256 + tid;
      int row = idx >> 2, c8 = (idx & 3) * 8;   // 64B rows of 32 bf16
      gl2lds16(Ag + row * K_ + k0 + c8, (char*)As[buf] + idx * 16);
      gl2lds16(Bg + row * K_ + k0 + c8, (char*)Bs[buf] + idx * 16);
    }
  };

  const int NT = K_ / BK;
  stage(0, 0);
  stage(1, BK);
  for (int t = 0; t < NT; ++t){
    if (t + 1 < NT)
      asm volatile("s_waitcnt vmcnt(4)" ::: "memory");  // tile t landed (mine)
    else
      asm volatile("s_waitcnt vmcnt(0)" ::: "memory");
    __builtin_amdgcn_s_barrier();      // all waves: tile t landed, iter t-1 reads done
    __builtin_amdgcn_sched_barrier(0);
    if (t + 2 < NT)
      stage((t + 2) % 3, (t + 2) * BK);        // safe: buf last read at t-1
    __builtin_amdgcn_sched_barrier(0);

    const short* Ac = As[t % 3];
    const short* Bc = Bs[t % 3];
    bf16x8 a[4], b[4];
#pragma unroll
    for (int mf = 0; mf < 4; mf++)
      a[mf] = *(const bf16x8*)(Ac + (wm * 64 + mf * 16 + lr) * BK + lk * 8);
#pragma unroll
    for (int nf = 0; nf < 4; nf++)
      b[nf] = *(const bf16x8*)(Bc + (wn * 64 + nf * 16 + lr) * BK + lk * 8);
    __builtin_amdgcn_s_setprio(1);
#pragma unroll
    for (int mf = 0; mf < 4; mf++)
#pragma unroll
      for (int nf = 0; nf < 4; nf++)
        acc[mf][nf] = __builtin_amdgcn_mfma_f32_16x16x32_bf16(a[mf], b[nf], acc[mf][nf], 0, 0, 0);
    __builtin_amdgcn_s_setprio(0);
    // no end barrier: next iter's top barrier separates reads from restage
  }

#pragma unroll
  for (int nf = 0; nf < 4; nf++){
    int n = bcol + wn * 64 + nf * 16 + lr;
    float bv = bias[n];
#pragma unroll
    for (int mf = 0; mf < 4; mf++){
      int m0 = brow + wm * 64 + mf * 16 + lk * 4;
#pragma unroll
      for (int r = 0; r < 4; r++)
        outf[(m0 + r) * N_ + n] = acc[mf][nf][r] + bv;
    }
  }
}

// ---------------- causal flash attention, 32x32 swapped-QK^T ----------------
// NS=4 kv-chunked split; partials Op bf16 + ml f32; merged by attn_merge.
// 256 thr / 4 waves; VGPR ~100 -> 4 waves/SIMD cap (HW: 32 waves/CU needs
// <=64 VGPR, impossible here); 16 waves/CU is this kernel's max.
__device__ inline int crow(int r, int h){ return (r & 3) + 8 * (r >> 2) + 4 * h; }

template<int NS>
__global__ __launch_bounds__(256, 4) void attn32(
    const short* __restrict__ Q, const short* __restrict__ Kg,
    const short* __restrict__ Vt, short* __restrict__ Y,
    short* __restrict__ Op, float* __restrict__ ml){
  __shared__ short Ks[2][64 * 64];
  __shared__ short Vs[2][64 * 64];
  __shared__ float bounce[4][32];
  const int tid = threadIdx.x;
  const int w = tid >> 6, l = tid & 63;
  const int lq = l & 31, h = l >> 5;
  const int bx = blockIdx.x;
  int i, hf;
  if constexpr (NS == 4){
    int u = bx >> 5, v = u & 15;
    i = (v < 8) ? 15 - v : v - 8;
    hf = u >> 4;
  } else {
    i = (bx < 256) ? 15 - (bx >> 5) : (bx >> 5) - 8;
    hf = 0;
  }
  const int bh = bx & 31;
  const int q0 = i * 128, qw = q0 + w * 32;
  const int nt = 2 * (i + 1);
  const int t0 = hf * nt / NS;
  const int t1 = (hf + 1) * nt / NS;

  // Q fragments (B-operand): qb[dk] = Q[qw+lq][16*dk + 8*h .. +7]
  bf16x8 qb[4];
  {
    const short* qbase = Q + (bh * T_ + qw + lq) * HD_;
#pragma unroll
    for (int dk = 0; dk < 4; dk++)
      qb[dk] = *(const bf16x8*)(qbase + dk * 16 + h * 8);
  }

  f32x16 o0 = {}, o1 = {};
  float m = -1e30f, ll = 0.f;

  auto stage = [&](int buf, int t){
#pragma unroll
    for (int j = 0; j < 2; j++){
      int idx = j * 256 + tid;
      int row = idx >> 3, cb = (idx & 7) * 16;     // 128B rows
      int cbs = cb ^ ((row & 7) << 4);
      gl2lds16(Kg + (bh * T_ + t * 64 + row) * HD_ + (cbs >> 1), (char*)Ks[buf] + idx * 16);
      gl2lds16(Vt + (bh * HD_ + row) * T_ + t * 64 + (cbs >> 1), (char*)Vs[buf] + idx * 16);
    }
  };

  if (t0 < t1){
    stage(0, t0);
    for (int t = t0; t < t1; ++t){
      const int cur = (t - t0) & 1;
      if (t + 1 < t1){
        stage(cur ^ 1, t + 1);                            // prefetch next tile
        asm volatile("s_waitcnt vmcnt(4)" ::: "memory");  // current tile landed
      } else {
        asm volatile("s_waitcnt vmcnt(0)" ::: "memory");
      }
      __builtin_amdgcn_s_barrier();
      __builtin_amdgcn_sched_barrier(0);

      const int kvb = t * 64;
      if (kvb <= qw + 31){                  // warp still below/on its diagonal
        const short* Kc = Ks[cur];
        const short* Vc = Vs[cur];

        // S^T = K . Q^T : s[kb] covers kv [kvb+32*kb, +32), q col = lq
        f32x16 s[2] = {};
        __builtin_amdgcn_s_setprio(1);
#pragma unroll
        for (int kb = 0; kb < 2; kb++){
          int row = kb * 32 + lq;
          const char* rp = (const char*)Kc + row * 128;
          int swz = (row & 7) << 4;
#pragma unroll
          for (int dk = 0; dk < 4; dk++){
            bf16x8 ka = *(const bf16x8*)(rp + ((dk * 32 + h * 16) ^ swz));
            s[kb] = __builtin_amdgcn_mfma_f32_32x32x16_bf16(ka, qb[dk], s[kb], 0, 0, 0);
          }
        }
        __builtin_amdgcn_s_setprio(0);

        const int qg = qw + lq;
        if (kvb + 63 > qw){                 // diagonal tile: causal mask
#pragma unroll
          for (int kb = 0; kb < 2; kb++)
#pragma unroll
            for (int r = 0; r < 16; r++){
              int kv = kvb + kb * 32 + crow(r, h);
              if (kv > qg) s[kb][r] = -1e30f;
            }
        }

        // row max: lane-local + 1 cross-half shuffle
        float pm = s[0][0];
#pragma unroll
        for (int r = 1; r < 16; r++) pm = fmaxf(pm, s[0][r]);
#pragma unroll
        for (int r = 0; r < 16; r++) pm = fmaxf(pm, s[1][r]);
        pm = fmaxf(pm, __shfl_xor(pm, 32));

        // defer-max (T13): rescale O only when max grew > 8 (log2 domain)
        if (__any(pm > m + 8.f)){
          float mn = fmaxf(pm, m);
          float sf = __builtin_amdgcn_exp2f(m - mn);
          m = mn;
          ll *= sf;
          bounce[w][lq] = sf;               // lanes l and l+32 write same value
#pragma unroll
          for (int r = 0; r < 16; r++){
            float sr = bounce[w][crow(r, h)];
            o0[r] *= sr; o1[r] *= sr;
          }
        }

        // P = 2^(s - m); row sum
        float ts = 0.f;
#pragma unroll
        for (int kb = 0; kb < 2; kb++)
#pragma unroll
          for (int r = 0; r < 16; r++){
            float p = __builtin_amdgcn_exp2f(s[kb][r] - m);
            s[kb][r] = p;
            ts += p;
          }
        ts += __shfl_xor(ts, 32);
        ll += ts;

        // pack P to bf16 pairs; pw0[kb*4+g] = kv kb*32+8g+4h'+{0,1}, pw1: +{2,3}
        unsigned pw0[8], pw1[8];
#pragma unroll
        for (int kb = 0; kb < 2; kb++)
#pragma unroll
          for (int gg = 0; gg < 4; gg++){
            unsigned r0, r1;
            asm("v_cvt_pk_bf16_f32 %0, %1, %2" : "=v"(r0) : "v"(s[kb][gg * 4 + 0]), "v"(s[kb][gg * 4 + 1]));
            asm("v_cvt_pk_bf16_f32 %0, %1, %2" : "=v"(r1) : "v"(s[kb][gg * 4 + 2]), "v"(s[kb][gg * 4 + 3]));
            pw0[kb * 4 + gg] = r0;
            pw1[kb * 4 + gg] = r1;
          }
        // swap(D=even, S=odd): D_hi <-> S_lo. even reg -> A-word0, odd -> A-word2.
#pragma unroll
        for (int ks = 0; ks < 4; ks++){
          asm("v_permlane32_swap_b32 %0, %1" : "+v"(pw0[2 * ks]), "+v"(pw0[2 * ks + 1]));
          asm("v_permlane32_swap_b32 %0, %1" : "+v"(pw1[2 * ks]), "+v"(pw1[2 * ks + 1]));
        }

        // O += P @ V
        __builtin_amdgcn_s_setprio(1);
#pragma unroll
        for (int ks = 0; ks < 4; ks++){
          uint4v paw;
          paw[0] = pw0[2 * ks];     paw[1] = pw1[2 * ks];
          paw[2] = pw0[2 * ks + 1]; paw[3] = pw1[2 * ks + 1];
          bf16x8 pa = __builtin_bit_cast(bf16x8, paw);
#pragma unroll
          for (int nb = 0; nb < 2; nb++){
            int row = nb * 32 + lq;
            bf16x8 vb = *(const bf16x8*)((const char*)Vc + row * 128 +
                          ((ks * 32 + h * 16) ^ ((row & 7) << 4)));
            if (nb == 0) o0 = __builtin_amdgcn_mfma_f32_32x32x16_bf16(pa, vb, o0, 0, 0, 0);
            else         o1 = __builtin_amdgcn_mfma_f32_32x32x16_bf16(pa, vb, o1, 0, 0, 0);
          }
        }
        __builtin_amdgcn_s_setprio(0);
      }
      __builtin_amdgcn_sched_barrier(0);
      __builtin_amdgcn_s_barrier();        // all reads of buf[cur] done
    }
  }

  if constexpr (NS == 4){
    // store unnormalized partials (bf16) + per-row (m, l)
    short* Oq = Op + ((size_t)(hf * 32 + bh)) * (size_t)T_ * 64;
    if (h == 0){
      float* mlr = ml + ((size_t)(hf * 32 + bh) * T_ + (qw + lq)) * 2;
      mlr[0] = m; mlr[1] = ll;
    }
#pragma unroll
    for (int r = 0; r < 16; r++){
      int qg = qw + crow(r, h);
      Oq[qg * 64 + lq]      = f2bf(o0[r]);
      Oq[qg * 64 + 32 + lq] = f2bf(o1[r]);
    }
  } else {
    // normalize by 1/l (broadcast via warp-private LDS) and store
    bounce[w][lq] = __builtin_amdgcn_rcpf(ll);
    const int b = bh >> 4, hh = bh & 15;
#pragma unroll
    for (int r = 0; r < 16; r++){
      int row = crow(r, h);
      float rl = bounce[w][row];
      int qg = qw + row;
      short* yb = Y + (b * T_ + qg) * D_ + hh * 64;
      yb[lq]      = f2bf(o0[r] * rl);
      yb[32 + lq] = f2bf(o1[r] * rl);
    }
  }
}

// ---------------- merge the four kv-split chunks ----------------
__global__ __launch_bounds__(256) void attn_merge(
    const short* __restrict__ Op, const float* __restrict__ ml,
    short* __restrict__ Y){
  int gid = blockIdx.x * 256 + threadIdx.x;
  int rid = gid >> 2, c16 = (gid & 3) * 16;
  float mh[4], lh[4];
#pragma unroll
  for (int hf = 0; hf < 4; hf++){
    float2 v = *(const float2*)(ml + (size_t)hf * 131072 + rid * 2);
    mh[hf] = v.x; lh[hf] = v.y;
  }
  float M = fmaxf(fmaxf(mh[0], mh[1]), fmaxf(mh[2], mh[3]));
  float f[4], den = 0.f;
#pragma unroll
  for (int hf = 0; hf < 4; hf++){
    f[hf] = __builtin_amdgcn_exp2f(mh[hf] - M);
    den += f[hf] * lh[hf];
  }
  float rl = 1.f / den;
  float acc[16] = {};
#pragma unroll
  for (int hf = 0; hf < 4; hf++){
    const short* o = Op + (size_t)hf * 4194304 + (size_t)rid * 64 + c16;
    bf16x8 a = *(const bf16x8*)(o);
    bf16x8 b = *(const bf16x8*)(o + 8);
    float fh = f[hf];
#pragma unroll
    for (int j = 0; j < 8; j++){
      acc[j]     += fh * bf2f(a[j]);
      acc[8 + j] += fh * bf2f(b[j]);
    }
  }
  int bh = rid >> 11, t = rid & 2047;
  short* yb = Y + (((bh >> 4) * T_ + t) * D_) + (bh & 15) * 64 + c16;
  bf16x8 o0, o1;
#pragma unroll
  for (int j = 0; j < 8; j++){
    o0[j] = f2bf(acc[j] * rl);
    o1[j] = f2bf(acc[8 + j] * rl);
  }
  *(bf16x8*)(yb)     = o0;
  *(bf16x8*)(yb + 8) = o1;
}

// ---------------- launch ----------------
extern "C" void kernel_launch(void* const* d_in, const int* in_sizes, int n_in,
                              void* d_out, int out_size, void* d_ws, size_t ws_size,
                              hipStream_t stream) {
  const float* x  = (const float*)d_in[0];
  const float* W1 = (const float*)d_in[1];
  const float* b1 = (const float*)d_in[2];
  const float* W2 = (const float*)d_in[3];
  const float* b2 = (const float*)d_in[4];
  float* out = (float*)d_out;

  char* ws = (char*)d_ws;
  short* W1T = (short*)(ws);                         // [3072][1024] bf16, 6 MB
  short* W2T = (short*)(ws + 6291456);               // [1024][1024] bf16, 2 MB
  short* xb  = (short*)(ws + 8388608);               // [4096][1024] bf16, 8 MB
  short* q   = (short*)(ws + 16777216);              // [B,H,T,64]  bf16, 8 MB
  short* kk  = (short*)(ws + 25165824);               // [B,H,T,64]  bf16, 8 MB
  short* vT  = (short*)(ws + 33554432);              // [B,H,64,T]  bf16, 8 MB
  short* Op  = (short*)(ws + 41943040);              // [4][32][2048][64] bf16, 32 MB
  float* mlb = (float*)(ws);                         // [4][32][2048][2] f32, 2 MB
                                                     //   overlays W1T (dead after QKV)
  short* y   = xb;                                   // alias: xb dead after QKV GEMM

  const size_t need = 41943040ull + 33554432ull;     // 72 MB
  const bool split = ws_size >= need;

  prep<<<dim3(8192), dim3(256), 0, stream>>>(x, xb, W1, W1T, W2, W2T);
  gemm_qkv8<<<dim3(16, 16), dim3(512), 0, stream>>>(xb, W1T, b1, q, kk, vT);
  if (split){
    attn32<4><<<dim3(2048), dim3(256), 0, stream>>>(q, kk, vT, nullptr, Op, mlb);
    attn_merge<<<dim3(1024), dim3(256), 0, stream>>>(Op, mlb, y);
  } else {
    attn32<1><<<dim3(512), dim3(256), 0, stream>>>(q, kk, vT, y, nullptr, nullptr);
  }
  gemm_bt<1024, 1024><<<dim3(8, 32), dim3(256), 0, stream>>>(y, W2T, b2, out);
}